// Round 6
// baseline (2064.818 us; speedup 1.0000x reference)
//
#include <hip/hip_runtime.h>

#define IMG 1024

typedef _Float16 half8 __attribute__((ext_vector_type(8)));
typedef float f32x4 __attribute__((ext_vector_type(4)));
typedef float f32x16 __attribute__((ext_vector_type(16)));

__device__ __forceinline__ int refl(int i) {
    i = (i < 0) ? -i : i;
    return (i >= IMG) ? (2 * IMG - 2 - i) : i;
}
__device__ __forceinline__ float afix(float a) { return (a < 0.001f) ? 1.0f : a; }
__device__ __forceinline__ int iclamp(int v, int lo, int hi) { return v < lo ? lo : (v > hi ? hi : v); }
__device__ __forceinline__ int swz64(int a) { return a ^ (((((a >> 6) & 3) ^ ((a >> 8) & 1)) << 4)); }
__device__ __forceinline__ int swz32(int a) { return a ^ ((((a >> 7) & 1)) << 4); }
__device__ __forceinline__ unsigned short h2b(_Float16 h) { union { _Float16 f; unsigned short u; } x; x.f = h; return x.u; }

// ---------------------------------------------------------------------------
// Weight prep. conv1/conv2 -> 32x32x16 A fragments (32 oc x 16 k), fp16 hi/lo.
//   A lane l: row(oc)=l&31, k-slot ii=(l>>5)*8+e  (16x16x32-verified pattern, M=32 analog)
//   conv1 ch = ii (linear, ic pad 12->16), frag idx f=(ky*7+kx)*2+pl
//   conv2 ch = (i&3)+8*(i>>2)+4*kh  (matches conv1/conv2 C-write layout), i=(l>>5)*8+e
//            frag idx ff=((ky*5+kx)*2+kh)*2+pl
// conv3 -> 16x16x32 A (16 oc-pad x 32 k): row=l&15, q=(l>>4)*8+e,
//   i=q&15, hl=q>>4, ch=(i&3)+8*(i>>2)+4*hl
// ---------------------------------------------------------------------------
__global__ void wprep_kernel(const float* __restrict__ w1, const float* __restrict__ w2,
                             const float* __restrict__ w3,
                             char* __restrict__ w1p, char* __restrict__ w2p, char* __restrict__ w3p)
{
    const int NF1 = 98, NF2 = 100, NF3 = 50;
    int gid = blockIdx.x * 256 + threadIdx.x;
    int f = gid >> 6, l = gid & 63;
    if (f >= NF1 + NF2 + NF3) return;
    half8 out;
    char* dst;
    if (f < NF1) {
        int pl = f & 1, kk = f >> 1;
        int kx = kk % 7, ky = kk / 7;
        int oc = l & 31;
#pragma unroll
        for (int e = 0; e < 8; e++) {
            int ii = (l >> 5) * 8 + e;
            float v = (ii < 12) ? w1[((oc * 12 + ii) * 7 + ky) * 7 + kx] : 0.f;
            _Float16 h = (_Float16)v;
            out[e] = pl ? (_Float16)(v - (float)h) : h;
        }
        dst = w1p + (size_t)f * 1024 + l * 16;
    } else if (f < NF1 + NF2) {
        int ff = f - NF1;
        int pl = ff & 1, kh = (ff >> 1) & 1, kk = ff >> 2;
        int kx = kk % 5, ky = kk / 5;
        int oc = l & 31;
#pragma unroll
        for (int e = 0; e < 8; e++) {
            int i = (l >> 5) * 8 + e;
            int ch = (i & 3) + 8 * (i >> 2) + 4 * kh;
            float v = w2[((oc * 32 + ch) * 5 + ky) * 5 + kx];
            _Float16 h = (_Float16)v;
            out[e] = pl ? (_Float16)(v - (float)h) : h;
        }
        dst = w2p + (size_t)ff * 1024 + l * 16;
    } else {
        int ff = f - NF1 - NF2;
        int pl = ff & 1, kk = ff >> 1;
        int kx = kk % 5, ky = kk / 5;
        int r = l & 15;
#pragma unroll
        for (int e = 0; e < 8; e++) {
            int q = (l >> 4) * 8 + e;
            int i = q & 15, hl = q >> 4;
            int ch = (i & 3) + 8 * (i >> 2) + 4 * hl;
            float v = (r < 8) ? w3[((r * 32 + ch) * 5 + ky) * 5 + kx] : 0.f;
            _Float16 h = (_Float16)v;
            out[e] = pl ? (_Float16)(v - (float)h) : h;
        }
        dst = w3p + (size_t)ff * 1024 + l * 16;
    }
    *(half8*)dst = out;
}

// ---------------------------------------------------------------------------
// net_in prep: transform + scale 1/4 + fp16 hi/lo split. [y][x][16ch] 32B/px.
// ---------------------------------------------------------------------------
__global__ void netin_kernel(const float* __restrict__ in, char* __restrict__ nh, char* __restrict__ nl)
{
    const int M = IMG * IMG;
    int px = blockIdx.x * 256 + threadIdx.x;
    float v[16];
#pragma unroll
    for (int c = 0; c < 3; c++) {
        float a = afix(in[(size_t)(c + 3) * M + px]);
        v[c] = (in[(size_t)c * M + px] / a) * 0.25f;
        v[c + 3] = a * 0.25f;
    }
#pragma unroll
    for (int c = 6; c < 12; c++) v[c] = in[(size_t)c * M + px] * 0.25f;
#pragma unroll
    for (int c = 12; c < 16; c++) v[c] = 0.f;
    unsigned short hb[16], lb[16];
#pragma unroll
    for (int c = 0; c < 16; c++) {
        _Float16 h = (_Float16)v[c];
        hb[c] = h2b(h);
        lb[c] = h2b((_Float16)(v[c] - (float)h));
    }
    *(int4*)(nh + (size_t)px * 32) = *(int4*)&hb[0];
    *(int4*)(nh + (size_t)px * 32 + 16) = *(int4*)&hb[8];
    *(int4*)(nl + (size_t)px * 32) = *(int4*)&lb[0];
    *(int4*)(nl + (size_t)px * 32 + 16) = *(int4*)&lb[8];
}

// ---------------------------------------------------------------------------
// conv1 compute: 32x32x16, diagonal s=r+ky dedup of B reads.
// ---------------------------------------------------------------------------
__device__ __forceinline__ void conv1_compute(const char* sm, const char* __restrict__ w1p,
                                              f32x16 acc[4], int l, int rbase, bool two)
{
    const int px = l & 31, hl = l >> 5;
#pragma unroll 1
    for (int kx = 0; kx < 7; kx++) {
        const int off = swz32((kx + px) * 32 + hl * 16);
#pragma unroll
        for (int s = 0; s < 10; s++) {
            half8 b = *(const half8*)(sm + (rbase + s) * 1280 + off);
#pragma unroll
            for (int ky = 0; ky < 7; ky++) {
                const int r = s - ky;
                if (r >= 0 && r < 4) {
                    const char* wb = w1p + (size_t)((ky * 7 + kx) * 2) * 1024 + l * 16;
                    acc[r] = __builtin_amdgcn_mfma_f32_32x32x16_f16(*(const half8*)wb, b, acc[r], 0, 0, 0);
                    if (two)
                        acc[r] = __builtin_amdgcn_mfma_f32_32x32x16_f16(*(const half8*)(wb + 1024), b, acc[r], 0, 0, 0);
                }
            }
        }
    }
}

// conv1: 12(pad16) -> 32, 7x7 reflect. 128 thr / 2 waves; wave 32px x 32oc x 4r.
__global__ __launch_bounds__(128, 2) void conv1_mfma(
    const char* __restrict__ nh, const char* __restrict__ nl,
    const char* __restrict__ w1p, const float* __restrict__ b1,
    char* __restrict__ h1h, char* __restrict__ h1l, int a1, int e1)
{
    __shared__ __align__(16) char sm[14 * 1280];
    const int t = threadIdx.x, l = t & 63, w = t >> 6;
    const int px = l & 31, hl = l >> 5;
    const int x0 = blockIdx.x * 32;
    const int ystart = a1 + blockIdx.y * 8;
    const int rbase = w * 4;
    const bool fast = (x0 >= 3) && (x0 + 37 <= IMG) && (ystart >= 3) && (ystart + 11 <= IMG);

    f32x16 acc[4];
#pragma unroll
    for (int r = 0; r < 4; r++)
#pragma unroll
        for (int i = 0; i < 16; i++) acc[r][i] = 0.f;

    // pass 1: hi plane
    if (fast) {
        const char* rb = nh + ((size_t)(ystart - 3) * IMG + (x0 - 3)) * 32;
        for (int q = t; q < 1120; q += 128) {
            int slab = q / 80, c2 = q % 80;
            *(int4*)(sm + slab * 1280 + swz32(c2 * 16)) = *(const int4*)(rb + (size_t)slab * (IMG * 32) + c2 * 16);
        }
    } else {
        for (int q = t; q < 1120; q += 128) {
            int slab = q / 80, c2 = q % 80;
            int gy = refl(ystart + slab - 3), gx = refl(x0 + (c2 >> 1) - 3);
            *(int4*)(sm + slab * 1280 + swz32(c2 * 16)) =
                *(const int4*)(nh + ((size_t)gy * IMG + gx) * 32 + (c2 & 1) * 16);
        }
    }
    __syncthreads();
    conv1_compute(sm, w1p, acc, l, rbase, true);
    __syncthreads();
    // pass 2: lo plane
    if (fast) {
        const char* rb = nl + ((size_t)(ystart - 3) * IMG + (x0 - 3)) * 32;
        for (int q = t; q < 1120; q += 128) {
            int slab = q / 80, c2 = q % 80;
            *(int4*)(sm + slab * 1280 + swz32(c2 * 16)) = *(const int4*)(rb + (size_t)slab * (IMG * 32) + c2 * 16);
        }
    } else {
        for (int q = t; q < 1120; q += 128) {
            int slab = q / 80, c2 = q % 80;
            int gy = refl(ystart + slab - 3), gx = refl(x0 + (c2 >> 1) - 3);
            *(int4*)(sm + slab * 1280 + swz32(c2 * 16)) =
                *(const int4*)(nl + ((size_t)gy * IMG + gx) * 32 + (c2 & 1) * 16);
        }
    }
    __syncthreads();
    conv1_compute(sm, w1p, acc, l, rbase, false);

#pragma unroll
    for (int r = 0; r < 4; r++) {
        int y = ystart + rbase + r;
        if (y < e1) {
            int x = x0 + px, ybuf = y - a1;
            unsigned short hb[16], lb[16];
#pragma unroll
            for (int i = 0; i < 16; i++) {
                int oc = (i & 3) + 8 * (i >> 2) + 4 * hl;
                float v = acc[r][i] * 4.f + b1[oc];
                v = fmaxf(v, 0.f) * 0.125f;
                _Float16 h = (_Float16)v;
                hb[i] = h2b(h);
                lb[i] = h2b((_Float16)(v - (float)h));
            }
            size_t ob = ((size_t)ybuf * IMG + x) * 64 + hl * 32;
            *(int4*)(h1h + ob) = *(int4*)&hb[0];
            *(int4*)(h1h + ob + 16) = *(int4*)&hb[8];
            *(int4*)(h1l + ob) = *(int4*)&lb[0];
            *(int4*)(h1l + ob + 16) = *(int4*)&lb[8];
        }
    }
}

// ---------------------------------------------------------------------------
// conv2 compute: 32x32x16, two k-halves, diagonal dedup.
// ---------------------------------------------------------------------------
__device__ __forceinline__ void conv2_compute(const char* sm, const char* __restrict__ wp,
                                              f32x16 acc[4], int l, int rbase, bool two)
{
    const int px = l & 31, hl = l >> 5;
#pragma unroll 1
    for (int kx = 0; kx < 5; kx++) {
        const int off0 = swz64((kx + px) * 64 + hl * 16);
        const int off1 = swz64((kx + px) * 64 + 32 + hl * 16);
#pragma unroll
        for (int s = 0; s < 8; s++) {
            const char* sl = sm + (rbase + s) * 2304;
            half8 bk0 = *(const half8*)(sl + off0);
            half8 bk1 = *(const half8*)(sl + off1);
#pragma unroll
            for (int ky = 0; ky < 5; ky++) {
                const int r = s - ky;
                if (r >= 0 && r < 4) {
                    const char* wb = wp + (size_t)((ky * 5 + kx) * 4) * 1024 + l * 16;
                    acc[r] = __builtin_amdgcn_mfma_f32_32x32x16_f16(*(const half8*)wb, bk0, acc[r], 0, 0, 0);
                    if (two)
                        acc[r] = __builtin_amdgcn_mfma_f32_32x32x16_f16(*(const half8*)(wb + 1024), bk0, acc[r], 0, 0, 0);
                    acc[r] = __builtin_amdgcn_mfma_f32_32x32x16_f16(*(const half8*)(wb + 2048), bk1, acc[r], 0, 0, 0);
                    if (two)
                        acc[r] = __builtin_amdgcn_mfma_f32_32x32x16_f16(*(const half8*)(wb + 3072), bk1, acc[r], 0, 0, 0);
                }
            }
        }
    }
}

// conv2: 32 -> 32, 5x5 reflect. 128 thr / 2 waves; wave 32px x 32oc x 4r.
__global__ __launch_bounds__(128, 2) void conv2_mfma(
    const char* __restrict__ h1h, const char* __restrict__ h1l,
    const char* __restrict__ w2p, const float* __restrict__ b2,
    char* __restrict__ h2h, char* __restrict__ h2l,
    int a1, int e1, int a2, int e2)
{
    __shared__ __align__(16) char sm[12 * 2304];
    const int t = threadIdx.x, l = t & 63, w = t >> 6;
    const int px = l & 31, hl = l >> 5;
    const int x0 = blockIdx.x * 32;
    const int ystart = a2 + blockIdx.y * 8;
    const int rbase = w * 4;
    const bool fast = (x0 >= 2) && (x0 + 34 <= IMG) && (ystart - 2 >= a1) && (ystart + 10 <= e1);

    f32x16 acc[4];
#pragma unroll
    for (int r = 0; r < 4; r++)
#pragma unroll
        for (int i = 0; i < 16; i++) acc[r][i] = 0.f;

    // pass 1: hi plane
    if (fast) {
        const char* rb = h1h + (((size_t)(ystart - 2 - a1)) * IMG + (x0 - 2)) * 64;
        for (int q = t; q < 1728; q += 128) {
            int slab = q / 144, c2 = q % 144;
            *(int4*)(sm + slab * 2304 + swz64(c2 * 16)) = *(const int4*)(rb + (size_t)slab * (IMG * 64) + c2 * 16);
        }
    } else {
        for (int q = t; q < 1728; q += 128) {
            int slab = q / 144, c2 = q % 144;
            int yy = iclamp(refl(ystart + slab - 2), a1, e1 - 1) - a1;
            int gx = refl(x0 + (c2 >> 2) - 2);
            *(int4*)(sm + slab * 2304 + swz64(c2 * 16)) =
                *(const int4*)(h1h + ((size_t)yy * IMG + gx) * 64 + (c2 & 3) * 16);
        }
    }
    __syncthreads();
    conv2_compute(sm, w2p, acc, l, rbase, true);
    __syncthreads();
    // pass 2: lo plane
    if (fast) {
        const char* rb = h1l + (((size_t)(ystart - 2 - a1)) * IMG + (x0 - 2)) * 64;
        for (int q = t; q < 1728; q += 128) {
            int slab = q / 144, c2 = q % 144;
            *(int4*)(sm + slab * 2304 + swz64(c2 * 16)) = *(const int4*)(rb + (size_t)slab * (IMG * 64) + c2 * 16);
        }
    } else {
        for (int q = t; q < 1728; q += 128) {
            int slab = q / 144, c2 = q % 144;
            int yy = iclamp(refl(ystart + slab - 2), a1, e1 - 1) - a1;
            int gx = refl(x0 + (c2 >> 2) - 2);
            *(int4*)(sm + slab * 2304 + swz64(c2 * 16)) =
                *(const int4*)(h1l + ((size_t)yy * IMG + gx) * 64 + (c2 & 3) * 16);
        }
    }
    __syncthreads();
    conv2_compute(sm, w2p, acc, l, rbase, false);

#pragma unroll
    for (int r = 0; r < 4; r++) {
        int y = ystart + rbase + r;
        if (y < e2) {
            int x = x0 + px, ybuf = y - a2;
            unsigned short hb[16], lb[16];
#pragma unroll
            for (int i = 0; i < 16; i++) {
                int oc = (i & 3) + 8 * (i >> 2) + 4 * hl;
                float v = acc[r][i] * 8.f + b2[oc];
                v = fmaxf(v, 0.f) * 0.125f;
                _Float16 h = (_Float16)v;
                hb[i] = h2b(h);
                lb[i] = h2b((_Float16)(v - (float)h));
            }
            size_t ob = ((size_t)ybuf * IMG + x) * 64 + hl * 32;
            *(int4*)(h2h + ob) = *(int4*)&hb[0];
            *(int4*)(h2h + ob + 16) = *(int4*)&hb[8];
            *(int4*)(h2l + ob) = *(int4*)&lb[0];
            *(int4*)(h2l + ob + 16) = *(int4*)&lb[8];
        }
    }
}

// ---------------------------------------------------------------------------
// conv3 compute: 16x16x32 (oc pad 8->16), diagonal dedup.
// ---------------------------------------------------------------------------
__device__ __forceinline__ void conv3_compute(const char* sm, const char* __restrict__ wp,
                                              f32x4 acc[4], int l, int pxt, int rbase, bool two)
{
    const int c = l & 15, g = l >> 4;
#pragma unroll 1
    for (int kx = 0; kx < 5; kx++) {
        const int off = swz64((pxt * 16 + c + kx) * 64 + g * 16);
#pragma unroll
        for (int s = 0; s < 8; s++) {
            half8 b = *(const half8*)(sm + (rbase + s) * 2304 + off);
#pragma unroll
            for (int ky = 0; ky < 5; ky++) {
                const int r = s - ky;
                if (r >= 0 && r < 4) {
                    const char* wb = wp + (size_t)((ky * 5 + kx) * 2) * 1024 + l * 16;
                    acc[r] = __builtin_amdgcn_mfma_f32_16x16x32_f16(*(const half8*)wb, b, acc[r], 0, 0, 0);
                    if (two)
                        acc[r] = __builtin_amdgcn_mfma_f32_16x16x32_f16(*(const half8*)(wb + 1024), b, acc[r], 0, 0, 0);
                }
            }
        }
    }
}

// conv3: 32 -> 8 (pad16), 5x5 reflect, fp32 logits. 256 thr / 4 waves.
__global__ __launch_bounds__(256, 4) void conv3_mfma(
    const char* __restrict__ h2h, const char* __restrict__ h2l,
    const char* __restrict__ w3p, const float* __restrict__ b3,
    float* __restrict__ lg, int a2, int e2, int r0, int r1, int rowsL)
{
    __shared__ __align__(16) char sm[12 * 2304];
    const int t = threadIdx.x, l = t & 63, w = t >> 6;
    const int c = l & 15, g = l >> 4;
    const int x0 = blockIdx.x * 32;
    const int ystart = r0 + blockIdx.y * 8;
    const int pxt = w & 1, rbase = (w >> 1) * 4;
    const bool fast = (x0 >= 2) && (x0 + 34 <= IMG) && (ystart - 2 >= a2) && (ystart + 10 <= e2);

    f32x4 acc[4];
#pragma unroll
    for (int r = 0; r < 4; r++) { acc[r][0] = 0.f; acc[r][1] = 0.f; acc[r][2] = 0.f; acc[r][3] = 0.f; }

    // pass 1: hi
    if (fast) {
        const char* rb = h2h + (((size_t)(ystart - 2 - a2)) * IMG + (x0 - 2)) * 64;
        for (int q = t; q < 1728; q += 256) {
            int slab = q / 144, c2 = q % 144;
            *(int4*)(sm + slab * 2304 + swz64(c2 * 16)) = *(const int4*)(rb + (size_t)slab * (IMG * 64) + c2 * 16);
        }
    } else {
        for (int q = t; q < 1728; q += 256) {
            int slab = q / 144, c2 = q % 144;
            int yy = iclamp(refl(ystart + slab - 2), a2, e2 - 1) - a2;
            int gx = refl(x0 + (c2 >> 2) - 2);
            *(int4*)(sm + slab * 2304 + swz64(c2 * 16)) =
                *(const int4*)(h2h + ((size_t)yy * IMG + gx) * 64 + (c2 & 3) * 16);
        }
    }
    __syncthreads();
    conv3_compute(sm, w3p, acc, l, pxt, rbase, true);
    __syncthreads();
    // pass 2: lo
    if (fast) {
        const char* rb = h2l + (((size_t)(ystart - 2 - a2)) * IMG + (x0 - 2)) * 64;
        for (int q = t; q < 1728; q += 256) {
            int slab = q / 144, c2 = q % 144;
            *(int4*)(sm + slab * 2304 + swz64(c2 * 16)) = *(const int4*)(rb + (size_t)slab * (IMG * 64) + c2 * 16);
        }
    } else {
        for (int q = t; q < 1728; q += 256) {
            int slab = q / 144, c2 = q % 144;
            int yy = iclamp(refl(ystart + slab - 2), a2, e2 - 1) - a2;
            int gx = refl(x0 + (c2 >> 2) - 2);
            *(int4*)(sm + slab * 2304 + swz64(c2 * 16)) =
                *(const int4*)(h2l + ((size_t)yy * IMG + gx) * 64 + (c2 & 3) * 16);
        }
    }
    __syncthreads();
    conv3_compute(sm, w3p, acc, l, pxt, rbase, false);

#pragma unroll
    for (int r = 0; r < 4; r++) {
        int y = ystart + rbase + r;
        if (y < r1 && g < 2) {
            int x = x0 + pxt * 16 + c, row = y - r0;
#pragma unroll
            for (int i = 0; i < 4; i++) {
                int oc = g * 4 + i;
                lg[((size_t)oc * rowsL + row) * IMG + x] = acc[r][i] * 8.f + b3[oc];
            }
        }
    }
}

// ---------------------------------------------------------------------------
// final: softmax(logits/5) + depthwise 7x7 zero-pad preconv + weighted sum +
// albedo remodulate. (fp32, unchanged.)
// ---------------------------------------------------------------------------
__global__ __launch_bounds__(256, 2) void final_kernel(
    const float* __restrict__ in, const float* __restrict__ lg, const float* __restrict__ dw,
    float* __restrict__ outp, int ylo, int yhi, int rowsL)
{
    __shared__ __align__(16) float sC[3][22][72];
    __shared__ __align__(16) float sdw[8][49];
    const int t = threadIdx.x;
    const int tx = t & 15, ty = t >> 4;
    const int x0 = blockIdx.x * 64;
    const int y0 = ylo + blockIdx.y * 16;

    for (int e = t; e < 8 * 49; e += 256) sdw[e / 49][e % 49] = dw[e];
    for (int e = t; e < 3 * 22 * 70; e += 256) {
        int c = e / (22 * 70), rem = e % (22 * 70);
        int r = rem / 70, cc = rem % 70;
        int gy = y0 + r - 3, gx = x0 + cc - 3;
        float v = 0.f;
        if (gy >= 0 && gy < IMG && gx >= 0 && gx < IMG) {
            float a = afix(in[(size_t)(c + 3) * IMG * IMG + (size_t)gy * IMG + gx]);
            v = in[(size_t)c * IMG * IMG + (size_t)gy * IMG + gx] / a;
        }
        sC[c][r][cc] = v;
    }
    __syncthreads();
    const int y = y0 + ty;
    if (y >= yhi) return;

    float lv[4][8];
#pragma unroll
    for (int k = 0; k < 8; k++) {
        float4 v = *(const float4*)&lg[((size_t)k * rowsL + (y - ylo)) * IMG + x0 + tx * 4];
        lv[0][k] = v.x; lv[1][k] = v.y; lv[2][k] = v.z; lv[3][k] = v.w;
    }
    float p[4][8];
#pragma unroll
    for (int j = 0; j < 4; j++) {
        float m = -3.4e38f;
#pragma unroll
        for (int k = 0; k < 8; k++) m = fmaxf(m, lv[j][k]);
        float s = 0.f;
#pragma unroll
        for (int k = 0; k < 8; k++) { float ev = __expf((lv[j][k] - m) * 0.2f); p[j][k] = ev; s += ev; }
        float invs = 1.0f / s;
#pragma unroll
        for (int k = 0; k < 8; k++) p[j][k] *= invs;
    }

    float filt[3][4];
#pragma unroll
    for (int c = 0; c < 3; c++)
#pragma unroll
        for (int j = 0; j < 4; j++) filt[c][j] = 0.f;

#pragma unroll 1
    for (int ky = 0; ky < 7; ky++) {
        float cv[3][10];
#pragma unroll
        for (int c = 0; c < 3; c++)
#pragma unroll
            for (int jj = 0; jj < 10; jj++) cv[c][jj] = sC[c][ty + ky][tx * 4 + jj];
#pragma unroll
        for (int kx = 0; kx < 7; kx++) {
            float dwv[8];
#pragma unroll
            for (int k = 0; k < 8; k++) dwv[k] = sdw[k][ky * 7 + kx];
#pragma unroll
            for (int j = 0; j < 4; j++) {
                float e0 = 0.f;
#pragma unroll
                for (int k = 0; k < 8; k++) e0 = fmaf(p[j][k], dwv[k], e0);
#pragma unroll
                for (int c = 0; c < 3; c++) filt[c][j] = fmaf(e0, cv[c][kx + j], filt[c][j]);
            }
        }
    }
#pragma unroll
    for (int c = 0; c < 3; c++) {
        const float* ap = &in[(size_t)(c + 3) * IMG * IMG + (size_t)y * IMG + x0 + tx * 4];
        float4 a4 = *(const float4*)ap;
        float4 o4 = make_float4(afix(a4.x) * filt[c][0], afix(a4.y) * filt[c][1],
                                afix(a4.z) * filt[c][2], afix(a4.w) * filt[c][3]);
        *(float4*)&outp[(size_t)c * IMG * IMG + (size_t)y * IMG + x0 + tx * 4] = o4;
    }
}

// ---------------------------------------------------------------------------
extern "C" void kernel_launch(void* const* d_in, const int* in_sizes, int n_in,
                              void* d_out, int out_size, void* d_ws, size_t ws_size,
                              hipStream_t stream)
{
    const float* in  = (const float*)d_in[0];
    const float* w1  = (const float*)d_in[1];
    const float* b1  = (const float*)d_in[2];
    const float* w2  = (const float*)d_in[3];
    const float* b2  = (const float*)d_in[4];
    const float* w3  = (const float*)d_in[5];
    const float* b3  = (const float*)d_in[6];
    const float* dw  = (const float*)d_in[7];
    float* out = (float*)d_out;

    const size_t WB1 = 98 * 1024, WB2 = 100 * 1024, WB3 = 50 * 1024;
    const size_t NETIN = (size_t)IMG * IMG * 32;  // bytes per plane

    int S = 1024;
    while (S > 64) {
        size_t need = WB1 + WB2 + WB3 + 2 * NETIN
                    + 2ull * (S + 8) * IMG * 64 + 2ull * (S + 4) * IMG * 64
                    + (size_t)S * IMG * 8 * 4;
        if (need <= ws_size) break;
        S >>= 1;
    }
    const int rows1 = S + 8, rows2 = S + 4, rowsL = S;

    char* w1p = (char*)d_ws;
    char* w2p = w1p + WB1;
    char* w3p = w2p + WB2;
    char* nh  = w3p + WB3;
    char* nl  = nh + NETIN;
    char* h1h = nl + NETIN;
    char* h1l = h1h + (size_t)rows1 * IMG * 64;
    char* h2h = h1l + (size_t)rows1 * IMG * 64;
    char* h2l = h2h + (size_t)rows2 * IMG * 64;
    float* lgb = (float*)(h2l + (size_t)rows2 * IMG * 64);

    wprep_kernel<<<62, 256, 0, stream>>>(w1, w2, w3, w1p, w2p, w3p);

    for (int b = 0; b < 4; b++) {
        const float* inb = in + (size_t)b * 12 * IMG * IMG;
        float* outb = out + (size_t)b * 3 * IMG * IMG;
        netin_kernel<<<IMG * IMG / 256, 256, 0, stream>>>(inb, nh, nl);
        for (int r0 = 0; r0 < IMG; r0 += S) {
            int r1 = r0 + S; if (r1 > IMG) r1 = IMG;
            int a1 = r0 - 4; if (a1 < 0) a1 = 0;
            int e1 = r1 + 4; if (e1 > IMG) e1 = IMG;
            int a2 = r0 - 2; if (a2 < 0) a2 = 0;
            int e2 = r1 + 2; if (e2 > IMG) e2 = IMG;
            conv1_mfma<<<dim3(32, (e1 - a1 + 7) / 8), 128, 0, stream>>>(nh, nl, w1p, b1, h1h, h1l, a1, e1);
            conv2_mfma<<<dim3(32, (e2 - a2 + 7) / 8), 128, 0, stream>>>(h1h, h1l, w2p, b2, h2h, h2l, a1, e1, a2, e2);
            conv3_mfma<<<dim3(32, (r1 - r0 + 7) / 8), 256, 0, stream>>>(h2h, h2l, w3p, b3, lgb, a2, e2, r0, r1, rowsL);
            final_kernel<<<dim3(16, (r1 - r0 + 15) / 16), 256, 0, stream>>>(inb, lgb, dw, outb, r0, r1, rowsL);
        }
    }
}

// Round 7
// 2042.317 us; speedup vs baseline: 1.0110x; 1.0110x over previous
//
#include <hip/hip_runtime.h>

#define IMG 1024

typedef _Float16 half8 __attribute__((ext_vector_type(8)));
typedef float f32x4 __attribute__((ext_vector_type(4)));
typedef float f32x16 __attribute__((ext_vector_type(16)));

__device__ __forceinline__ int refl(int i) {
    i = (i < 0) ? -i : i;
    return (i >= IMG) ? (2 * IMG - 2 - i) : i;
}
__device__ __forceinline__ float afix(float a) { return (a < 0.001f) ? 1.0f : a; }
__device__ __forceinline__ int iclamp(int v, int lo, int hi) { return v < lo ? lo : (v > hi ? hi : v); }
__device__ __forceinline__ int swz64(int a) { return a ^ (((((a >> 6) & 3) ^ ((a >> 8) & 1)) << 4)); }
__device__ __forceinline__ int swz32(int a) { return a ^ ((((a >> 7) & 1)) << 4); }
__device__ __forceinline__ unsigned short h2b(_Float16 h) { union { _Float16 f; unsigned short u; } x; x.f = h; return x.u; }

// ---------------------------------------------------------------------------
// Weight prep. conv1/conv2 -> 32x32x16 A fragments (32 oc x 16 k), fp16 hi/lo.
//   A lane l: row(oc)=l&31, k-slot ii=(l>>5)*8+e   (HW-verified in round 6)
//   conv1 ch = ii (linear, ic pad 12->16), frag idx f=(ky*7+kx)*2+pl
//   conv2 ch = (i&3)+8*(i>>2)+4*kh, i=(l>>5)*8+e; frag ff=((ky*5+kx)*2+kh)*2+pl
// conv3 -> 16x16x32 A (16 oc-pad x 32 k): row=l&15, q=(l>>4)*8+e,
//   i=q&15, hl=q>>4, ch=(i&3)+8*(i>>2)+4*hl
// ---------------------------------------------------------------------------
__global__ void wprep_kernel(const float* __restrict__ w1, const float* __restrict__ w2,
                             const float* __restrict__ w3,
                             char* __restrict__ w1p, char* __restrict__ w2p, char* __restrict__ w3p)
{
    const int NF1 = 98, NF2 = 100, NF3 = 50;
    int gid = blockIdx.x * 256 + threadIdx.x;
    int f = gid >> 6, l = gid & 63;
    if (f >= NF1 + NF2 + NF3) return;
    half8 out;
    char* dst;
    if (f < NF1) {
        int pl = f & 1, kk = f >> 1;
        int kx = kk % 7, ky = kk / 7;
        int oc = l & 31;
#pragma unroll
        for (int e = 0; e < 8; e++) {
            int ii = (l >> 5) * 8 + e;
            float v = (ii < 12) ? w1[((oc * 12 + ii) * 7 + ky) * 7 + kx] : 0.f;
            _Float16 h = (_Float16)v;
            out[e] = pl ? (_Float16)(v - (float)h) : h;
        }
        dst = w1p + (size_t)f * 1024 + l * 16;
    } else if (f < NF1 + NF2) {
        int ff = f - NF1;
        int pl = ff & 1, kh = (ff >> 1) & 1, kk = ff >> 2;
        int kx = kk % 5, ky = kk / 5;
        int oc = l & 31;
#pragma unroll
        for (int e = 0; e < 8; e++) {
            int i = (l >> 5) * 8 + e;
            int ch = (i & 3) + 8 * (i >> 2) + 4 * kh;
            float v = w2[((oc * 32 + ch) * 5 + ky) * 5 + kx];
            _Float16 h = (_Float16)v;
            out[e] = pl ? (_Float16)(v - (float)h) : h;
        }
        dst = w2p + (size_t)ff * 1024 + l * 16;
    } else {
        int ff = f - NF1 - NF2;
        int pl = ff & 1, kk = ff >> 1;
        int kx = kk % 5, ky = kk / 5;
        int r = l & 15;
#pragma unroll
        for (int e = 0; e < 8; e++) {
            int q = (l >> 4) * 8 + e;
            int i = q & 15, hl = q >> 4;
            int ch = (i & 3) + 8 * (i >> 2) + 4 * hl;
            float v = (r < 8) ? w3[((r * 32 + ch) * 5 + ky) * 5 + kx] : 0.f;
            _Float16 h = (_Float16)v;
            out[e] = pl ? (_Float16)(v - (float)h) : h;
        }
        dst = w3p + (size_t)ff * 1024 + l * 16;
    }
    *(half8*)dst = out;
}

// ---------------------------------------------------------------------------
// net_in prep: transform + scale 1/4 + fp16 hi/lo split. [y][x][16ch] 32B/px.
// ---------------------------------------------------------------------------
__global__ void netin_kernel(const float* __restrict__ in, char* __restrict__ nh, char* __restrict__ nl)
{
    const int M = IMG * IMG;
    int px = blockIdx.x * 256 + threadIdx.x;
    float v[16];
#pragma unroll
    for (int c = 0; c < 3; c++) {
        float a = afix(in[(size_t)(c + 3) * M + px]);
        v[c] = (in[(size_t)c * M + px] / a) * 0.25f;
        v[c + 3] = a * 0.25f;
    }
#pragma unroll
    for (int c = 6; c < 12; c++) v[c] = in[(size_t)c * M + px] * 0.25f;
#pragma unroll
    for (int c = 12; c < 16; c++) v[c] = 0.f;
    unsigned short hb[16], lb[16];
#pragma unroll
    for (int c = 0; c < 16; c++) {
        _Float16 h = (_Float16)v[c];
        hb[c] = h2b(h);
        lb[c] = h2b((_Float16)(v[c] - (float)h));
    }
    *(int4*)(nh + (size_t)px * 32) = *(int4*)&hb[0];
    *(int4*)(nh + (size_t)px * 32 + 16) = *(int4*)&hb[8];
    *(int4*)(nl + (size_t)px * 32) = *(int4*)&lb[0];
    *(int4*)(nl + (size_t)px * 32 + 16) = *(int4*)&lb[8];
}

// ---------------------------------------------------------------------------
// conv1 compute: 32x32x16, 2 rows/wave, diagonal s=r+ky dedup.
// ---------------------------------------------------------------------------
__device__ __forceinline__ void conv1_compute(const char* sm, const char* __restrict__ w1p,
                                              f32x16 acc[2], int l, int rbase, bool two)
{
    const int px = l & 31, hl = l >> 5;
#pragma unroll 1
    for (int kx = 0; kx < 7; kx++) {
        const int off = swz32((kx + px) * 32 + hl * 16);
#pragma unroll
        for (int s = 0; s < 8; s++) {
            half8 b = *(const half8*)(sm + (rbase + s) * 1280 + off);
#pragma unroll
            for (int ky = 0; ky < 7; ky++) {
                const int r = s - ky;
                if (r >= 0 && r < 2) {
                    const char* wb = w1p + (size_t)((ky * 7 + kx) * 2) * 1024 + l * 16;
                    acc[r] = __builtin_amdgcn_mfma_f32_32x32x16_f16(*(const half8*)wb, b, acc[r], 0, 0, 0);
                    if (two)
                        acc[r] = __builtin_amdgcn_mfma_f32_32x32x16_f16(*(const half8*)(wb + 1024), b, acc[r], 0, 0, 0);
                }
            }
        }
    }
}

// conv1: 12(pad16) -> 32, 7x7 reflect. 256 thr / 4 waves; wave 32px x 32oc x 2r.
__global__ __launch_bounds__(256, 4) void conv1_mfma(
    const char* __restrict__ nh, const char* __restrict__ nl,
    const char* __restrict__ w1p, const float* __restrict__ b1,
    char* __restrict__ h1h, char* __restrict__ h1l, int a1, int e1)
{
    __shared__ __align__(16) char sm[14 * 1280];
    const int t = threadIdx.x, l = t & 63, w = t >> 6;
    const int px = l & 31, hl = l >> 5;
    const int x0 = blockIdx.x * 32;
    const int ystart = a1 + blockIdx.y * 8;
    const int rbase = w * 2;
    const bool fast = (x0 >= 3) && (x0 + 37 <= IMG) && (ystart >= 3) && (ystart + 11 <= IMG);

    f32x16 acc[2];
#pragma unroll
    for (int r = 0; r < 2; r++)
#pragma unroll
        for (int i = 0; i < 16; i++) acc[r][i] = 0.f;

    // pass 1: hi plane
    if (fast) {
        const char* rb = nh + ((size_t)(ystart - 3) * IMG + (x0 - 3)) * 32;
        for (int q = t; q < 1120; q += 256) {
            int slab = q / 80, c2 = q % 80;
            *(int4*)(sm + slab * 1280 + swz32(c2 * 16)) = *(const int4*)(rb + (size_t)slab * (IMG * 32) + c2 * 16);
        }
    } else {
        for (int q = t; q < 1120; q += 256) {
            int slab = q / 80, c2 = q % 80;
            int gy = refl(ystart + slab - 3), gx = refl(x0 + (c2 >> 1) - 3);
            *(int4*)(sm + slab * 1280 + swz32(c2 * 16)) =
                *(const int4*)(nh + ((size_t)gy * IMG + gx) * 32 + (c2 & 1) * 16);
        }
    }
    __syncthreads();
    conv1_compute(sm, w1p, acc, l, rbase, true);
    __syncthreads();
    // pass 2: lo plane
    if (fast) {
        const char* rb = nl + ((size_t)(ystart - 3) * IMG + (x0 - 3)) * 32;
        for (int q = t; q < 1120; q += 256) {
            int slab = q / 80, c2 = q % 80;
            *(int4*)(sm + slab * 1280 + swz32(c2 * 16)) = *(const int4*)(rb + (size_t)slab * (IMG * 32) + c2 * 16);
        }
    } else {
        for (int q = t; q < 1120; q += 256) {
            int slab = q / 80, c2 = q % 80;
            int gy = refl(ystart + slab - 3), gx = refl(x0 + (c2 >> 1) - 3);
            *(int4*)(sm + slab * 1280 + swz32(c2 * 16)) =
                *(const int4*)(nl + ((size_t)gy * IMG + gx) * 32 + (c2 & 1) * 16);
        }
    }
    __syncthreads();
    conv1_compute(sm, w1p, acc, l, rbase, false);

#pragma unroll
    for (int r = 0; r < 2; r++) {
        int y = ystart + rbase + r;
        if (y < e1) {
            int x = x0 + px, ybuf = y - a1;
            unsigned short hb[16], lb[16];
#pragma unroll
            for (int i = 0; i < 16; i++) {
                int oc = (i & 3) + 8 * (i >> 2) + 4 * hl;
                float v = acc[r][i] * 4.f + b1[oc];
                v = fmaxf(v, 0.f) * 0.125f;
                _Float16 h = (_Float16)v;
                hb[i] = h2b(h);
                lb[i] = h2b((_Float16)(v - (float)h));
            }
            size_t ob = ((size_t)ybuf * IMG + x) * 64 + hl * 32;
            *(int4*)(h1h + ob) = *(int4*)&hb[0];
            *(int4*)(h1h + ob + 16) = *(int4*)&hb[8];
            *(int4*)(h1l + ob) = *(int4*)&lb[0];
            *(int4*)(h1l + ob + 16) = *(int4*)&lb[8];
        }
    }
}

// ---------------------------------------------------------------------------
// conv2 compute: 32x32x16, 2 rows/wave, two k-halves, diagonal dedup.
// ---------------------------------------------------------------------------
__device__ __forceinline__ void conv2_compute(const char* sm, const char* __restrict__ wp,
                                              f32x16 acc[2], int l, int rbase, bool two)
{
    const int px = l & 31, hl = l >> 5;
#pragma unroll 1
    for (int kx = 0; kx < 5; kx++) {
        const int off0 = swz64((kx + px) * 64 + hl * 16);
        const int off1 = swz64((kx + px) * 64 + 32 + hl * 16);
#pragma unroll
        for (int s = 0; s < 6; s++) {
            const char* sl = sm + (rbase + s) * 2304;
            half8 bk0 = *(const half8*)(sl + off0);
            half8 bk1 = *(const half8*)(sl + off1);
#pragma unroll
            for (int ky = 0; ky < 5; ky++) {
                const int r = s - ky;
                if (r >= 0 && r < 2) {
                    const char* wb = wp + (size_t)((ky * 5 + kx) * 4) * 1024 + l * 16;
                    acc[r] = __builtin_amdgcn_mfma_f32_32x32x16_f16(*(const half8*)wb, bk0, acc[r], 0, 0, 0);
                    if (two)
                        acc[r] = __builtin_amdgcn_mfma_f32_32x32x16_f16(*(const half8*)(wb + 1024), bk0, acc[r], 0, 0, 0);
                    acc[r] = __builtin_amdgcn_mfma_f32_32x32x16_f16(*(const half8*)(wb + 2048), bk1, acc[r], 0, 0, 0);
                    if (two)
                        acc[r] = __builtin_amdgcn_mfma_f32_32x32x16_f16(*(const half8*)(wb + 3072), bk1, acc[r], 0, 0, 0);
                }
            }
        }
    }
}

// conv2: 32 -> 32, 5x5 reflect. 256 thr / 4 waves; wave 32px x 32oc x 2r.
__global__ __launch_bounds__(256, 4) void conv2_mfma(
    const char* __restrict__ h1h, const char* __restrict__ h1l,
    const char* __restrict__ w2p, const float* __restrict__ b2,
    char* __restrict__ h2h, char* __restrict__ h2l,
    int a1, int e1, int a2, int e2)
{
    __shared__ __align__(16) char sm[12 * 2304];
    const int t = threadIdx.x, l = t & 63, w = t >> 6;
    const int px = l & 31, hl = l >> 5;
    const int x0 = blockIdx.x * 32;
    const int ystart = a2 + blockIdx.y * 8;
    const int rbase = w * 2;
    const bool fast = (x0 >= 2) && (x0 + 34 <= IMG) && (ystart - 2 >= a1) && (ystart + 10 <= e1);

    f32x16 acc[2];
#pragma unroll
    for (int r = 0; r < 2; r++)
#pragma unroll
        for (int i = 0; i < 16; i++) acc[r][i] = 0.f;

    // pass 1: hi plane
    if (fast) {
        const char* rb = h1h + (((size_t)(ystart - 2 - a1)) * IMG + (x0 - 2)) * 64;
        for (int q = t; q < 1728; q += 256) {
            int slab = q / 144, c2 = q % 144;
            *(int4*)(sm + slab * 2304 + swz64(c2 * 16)) = *(const int4*)(rb + (size_t)slab * (IMG * 64) + c2 * 16);
        }
    } else {
        for (int q = t; q < 1728; q += 256) {
            int slab = q / 144, c2 = q % 144;
            int yy = iclamp(refl(ystart + slab - 2), a1, e1 - 1) - a1;
            int gx = refl(x0 + (c2 >> 2) - 2);
            *(int4*)(sm + slab * 2304 + swz64(c2 * 16)) =
                *(const int4*)(h1h + ((size_t)yy * IMG + gx) * 64 + (c2 & 3) * 16);
        }
    }
    __syncthreads();
    conv2_compute(sm, w2p, acc, l, rbase, true);
    __syncthreads();
    // pass 2: lo plane
    if (fast) {
        const char* rb = h1l + (((size_t)(ystart - 2 - a1)) * IMG + (x0 - 2)) * 64;
        for (int q = t; q < 1728; q += 256) {
            int slab = q / 144, c2 = q % 144;
            *(int4*)(sm + slab * 2304 + swz64(c2 * 16)) = *(const int4*)(rb + (size_t)slab * (IMG * 64) + c2 * 16);
        }
    } else {
        for (int q = t; q < 1728; q += 256) {
            int slab = q / 144, c2 = q % 144;
            int yy = iclamp(refl(ystart + slab - 2), a1, e1 - 1) - a1;
            int gx = refl(x0 + (c2 >> 2) - 2);
            *(int4*)(sm + slab * 2304 + swz64(c2 * 16)) =
                *(const int4*)(h1l + ((size_t)yy * IMG + gx) * 64 + (c2 & 3) * 16);
        }
    }
    __syncthreads();
    conv2_compute(sm, w2p, acc, l, rbase, false);

#pragma unroll
    for (int r = 0; r < 2; r++) {
        int y = ystart + rbase + r;
        if (y < e2) {
            int x = x0 + px, ybuf = y - a2;
            unsigned short hb[16], lb[16];
#pragma unroll
            for (int i = 0; i < 16; i++) {
                int oc = (i & 3) + 8 * (i >> 2) + 4 * hl;
                float v = acc[r][i] * 8.f + b2[oc];
                v = fmaxf(v, 0.f) * 0.125f;
                _Float16 h = (_Float16)v;
                hb[i] = h2b(h);
                lb[i] = h2b((_Float16)(v - (float)h));
            }
            size_t ob = ((size_t)ybuf * IMG + x) * 64 + hl * 32;
            *(int4*)(h2h + ob) = *(int4*)&hb[0];
            *(int4*)(h2h + ob + 16) = *(int4*)&hb[8];
            *(int4*)(h2l + ob) = *(int4*)&lb[0];
            *(int4*)(h2l + ob + 16) = *(int4*)&lb[8];
        }
    }
}

// ---------------------------------------------------------------------------
// conv3 compute: 16x16x32 (oc pad 8->16), diagonal dedup. (unchanged)
// ---------------------------------------------------------------------------
__device__ __forceinline__ void conv3_compute(const char* sm, const char* __restrict__ wp,
                                              f32x4 acc[4], int l, int pxt, int rbase, bool two)
{
    const int c = l & 15, g = l >> 4;
#pragma unroll 1
    for (int kx = 0; kx < 5; kx++) {
        const int off = swz64((pxt * 16 + c + kx) * 64 + g * 16);
#pragma unroll
        for (int s = 0; s < 8; s++) {
            half8 b = *(const half8*)(sm + (rbase + s) * 2304 + off);
#pragma unroll
            for (int ky = 0; ky < 5; ky++) {
                const int r = s - ky;
                if (r >= 0 && r < 4) {
                    const char* wb = wp + (size_t)((ky * 5 + kx) * 2) * 1024 + l * 16;
                    acc[r] = __builtin_amdgcn_mfma_f32_16x16x32_f16(*(const half8*)wb, b, acc[r], 0, 0, 0);
                    if (two)
                        acc[r] = __builtin_amdgcn_mfma_f32_16x16x32_f16(*(const half8*)(wb + 1024), b, acc[r], 0, 0, 0);
                }
            }
        }
    }
}

// conv3: 32 -> 8 (pad16), 5x5 reflect, fp32 logits. 256 thr / 4 waves.
__global__ __launch_bounds__(256, 4) void conv3_mfma(
    const char* __restrict__ h2h, const char* __restrict__ h2l,
    const char* __restrict__ w3p, const float* __restrict__ b3,
    float* __restrict__ lg, int a2, int e2, int r0, int r1, int rowsL)
{
    __shared__ __align__(16) char sm[12 * 2304];
    const int t = threadIdx.x, l = t & 63, w = t >> 6;
    const int c = l & 15, g = l >> 4;
    const int x0 = blockIdx.x * 32;
    const int ystart = r0 + blockIdx.y * 8;
    const int pxt = w & 1, rbase = (w >> 1) * 4;
    const bool fast = (x0 >= 2) && (x0 + 34 <= IMG) && (ystart - 2 >= a2) && (ystart + 10 <= e2);

    f32x4 acc[4];
#pragma unroll
    for (int r = 0; r < 4; r++) { acc[r][0] = 0.f; acc[r][1] = 0.f; acc[r][2] = 0.f; acc[r][3] = 0.f; }

    // pass 1: hi
    if (fast) {
        const char* rb = h2h + (((size_t)(ystart - 2 - a2)) * IMG + (x0 - 2)) * 64;
        for (int q = t; q < 1728; q += 256) {
            int slab = q / 144, c2 = q % 144;
            *(int4*)(sm + slab * 2304 + swz64(c2 * 16)) = *(const int4*)(rb + (size_t)slab * (IMG * 64) + c2 * 16);
        }
    } else {
        for (int q = t; q < 1728; q += 256) {
            int slab = q / 144, c2 = q % 144;
            int yy = iclamp(refl(ystart + slab - 2), a2, e2 - 1) - a2;
            int gx = refl(x0 + (c2 >> 2) - 2);
            *(int4*)(sm + slab * 2304 + swz64(c2 * 16)) =
                *(const int4*)(h2h + ((size_t)yy * IMG + gx) * 64 + (c2 & 3) * 16);
        }
    }
    __syncthreads();
    conv3_compute(sm, w3p, acc, l, pxt, rbase, true);
    __syncthreads();
    // pass 2: lo
    if (fast) {
        const char* rb = h2l + (((size_t)(ystart - 2 - a2)) * IMG + (x0 - 2)) * 64;
        for (int q = t; q < 1728; q += 256) {
            int slab = q / 144, c2 = q % 144;
            *(int4*)(sm + slab * 2304 + swz64(c2 * 16)) = *(const int4*)(rb + (size_t)slab * (IMG * 64) + c2 * 16);
        }
    } else {
        for (int q = t; q < 1728; q += 256) {
            int slab = q / 144, c2 = q % 144;
            int yy = iclamp(refl(ystart + slab - 2), a2, e2 - 1) - a2;
            int gx = refl(x0 + (c2 >> 2) - 2);
            *(int4*)(sm + slab * 2304 + swz64(c2 * 16)) =
                *(const int4*)(h2l + ((size_t)yy * IMG + gx) * 64 + (c2 & 3) * 16);
        }
    }
    __syncthreads();
    conv3_compute(sm, w3p, acc, l, pxt, rbase, false);

#pragma unroll
    for (int r = 0; r < 4; r++) {
        int y = ystart + rbase + r;
        if (y < r1 && g < 2) {
            int x = x0 + pxt * 16 + c, row = y - r0;
#pragma unroll
            for (int i = 0; i < 4; i++) {
                int oc = g * 4 + i;
                lg[((size_t)oc * rowsL + row) * IMG + x] = acc[r][i] * 8.f + b3[oc];
            }
        }
    }
}

// ---------------------------------------------------------------------------
// final: softmax(logits/5) + depthwise 7x7 zero-pad preconv + weighted sum +
// albedo remodulate. (fp32, unchanged.)
// ---------------------------------------------------------------------------
__global__ __launch_bounds__(256, 2) void final_kernel(
    const float* __restrict__ in, const float* __restrict__ lg, const float* __restrict__ dw,
    float* __restrict__ outp, int ylo, int yhi, int rowsL)
{
    __shared__ __align__(16) float sC[3][22][72];
    __shared__ __align__(16) float sdw[8][49];
    const int t = threadIdx.x;
    const int tx = t & 15, ty = t >> 4;
    const int x0 = blockIdx.x * 64;
    const int y0 = ylo + blockIdx.y * 16;

    for (int e = t; e < 8 * 49; e += 256) sdw[e / 49][e % 49] = dw[e];
    for (int e = t; e < 3 * 22 * 70; e += 256) {
        int c = e / (22 * 70), rem = e % (22 * 70);
        int r = rem / 70, cc = rem % 70;
        int gy = y0 + r - 3, gx = x0 + cc - 3;
        float v = 0.f;
        if (gy >= 0 && gy < IMG && gx >= 0 && gx < IMG) {
            float a = afix(in[(size_t)(c + 3) * IMG * IMG + (size_t)gy * IMG + gx]);
            v = in[(size_t)c * IMG * IMG + (size_t)gy * IMG + gx] / a;
        }
        sC[c][r][cc] = v;
    }
    __syncthreads();
    const int y = y0 + ty;
    if (y >= yhi) return;

    float lv[4][8];
#pragma unroll
    for (int k = 0; k < 8; k++) {
        float4 v = *(const float4*)&lg[((size_t)k * rowsL + (y - ylo)) * IMG + x0 + tx * 4];
        lv[0][k] = v.x; lv[1][k] = v.y; lv[2][k] = v.z; lv[3][k] = v.w;
    }
    float p[4][8];
#pragma unroll
    for (int j = 0; j < 4; j++) {
        float m = -3.4e38f;
#pragma unroll
        for (int k = 0; k < 8; k++) m = fmaxf(m, lv[j][k]);
        float s = 0.f;
#pragma unroll
        for (int k = 0; k < 8; k++) { float ev = __expf((lv[j][k] - m) * 0.2f); p[j][k] = ev; s += ev; }
        float invs = 1.0f / s;
#pragma unroll
        for (int k = 0; k < 8; k++) p[j][k] *= invs;
    }

    float filt[3][4];
#pragma unroll
    for (int c = 0; c < 3; c++)
#pragma unroll
        for (int j = 0; j < 4; j++) filt[c][j] = 0.f;

#pragma unroll 1
    for (int ky = 0; ky < 7; ky++) {
        float cv[3][10];
#pragma unroll
        for (int c = 0; c < 3; c++)
#pragma unroll
            for (int jj = 0; jj < 10; jj++) cv[c][jj] = sC[c][ty + ky][tx * 4 + jj];
#pragma unroll
        for (int kx = 0; kx < 7; kx++) {
            float dwv[8];
#pragma unroll
            for (int k = 0; k < 8; k++) dwv[k] = sdw[k][ky * 7 + kx];
#pragma unroll
            for (int j = 0; j < 4; j++) {
                float e0 = 0.f;
#pragma unroll
                for (int k = 0; k < 8; k++) e0 = fmaf(p[j][k], dwv[k], e0);
#pragma unroll
                for (int c = 0; c < 3; c++) filt[c][j] = fmaf(e0, cv[c][kx + j], filt[c][j]);
            }
        }
    }
#pragma unroll
    for (int c = 0; c < 3; c++) {
        const float* ap = &in[(size_t)(c + 3) * IMG * IMG + (size_t)y * IMG + x0 + tx * 4];
        float4 a4 = *(const float4*)ap;
        float4 o4 = make_float4(afix(a4.x) * filt[c][0], afix(a4.y) * filt[c][1],
                                afix(a4.z) * filt[c][2], afix(a4.w) * filt[c][3]);
        *(float4*)&outp[(size_t)c * IMG * IMG + (size_t)y * IMG + x0 + tx * 4] = o4;
    }
}

// ---------------------------------------------------------------------------
extern "C" void kernel_launch(void* const* d_in, const int* in_sizes, int n_in,
                              void* d_out, int out_size, void* d_ws, size_t ws_size,
                              hipStream_t stream)
{
    const float* in  = (const float*)d_in[0];
    const float* w1  = (const float*)d_in[1];
    const float* b1  = (const float*)d_in[2];
    const float* w2  = (const float*)d_in[3];
    const float* b2  = (const float*)d_in[4];
    const float* w3  = (const float*)d_in[5];
    const float* b3  = (const float*)d_in[6];
    const float* dw  = (const float*)d_in[7];
    float* out = (float*)d_out;

    const size_t WB1 = 98 * 1024, WB2 = 100 * 1024, WB3 = 50 * 1024;
    const size_t NETIN = (size_t)IMG * IMG * 32;  // bytes per plane

    int S = 1024;
    while (S > 64) {
        size_t need = WB1 + WB2 + WB3 + 2 * NETIN
                    + 2ull * (S + 8) * IMG * 64 + 2ull * (S + 4) * IMG * 64
                    + (size_t)S * IMG * 8 * 4;
        if (need <= ws_size) break;
        S >>= 1;
    }
    const int rows1 = S + 8, rows2 = S + 4, rowsL = S;

    char* w1p = (char*)d_ws;
    char* w2p = w1p + WB1;
    char* w3p = w2p + WB2;
    char* nh  = w3p + WB3;
    char* nl  = nh + NETIN;
    char* h1h = nl + NETIN;
    char* h1l = h1h + (size_t)rows1 * IMG * 64;
    char* h2h = h1l + (size_t)rows1 * IMG * 64;
    char* h2l = h2h + (size_t)rows2 * IMG * 64;
    float* lgb = (float*)(h2l + (size_t)rows2 * IMG * 64);

    wprep_kernel<<<62, 256, 0, stream>>>(w1, w2, w3, w1p, w2p, w3p);

    for (int b = 0; b < 4; b++) {
        const float* inb = in + (size_t)b * 12 * IMG * IMG;
        float* outb = out + (size_t)b * 3 * IMG * IMG;
        netin_kernel<<<IMG * IMG / 256, 256, 0, stream>>>(inb, nh, nl);
        for (int r0 = 0; r0 < IMG; r0 += S) {
            int r1 = r0 + S; if (r1 > IMG) r1 = IMG;
            int a1 = r0 - 4; if (a1 < 0) a1 = 0;
            int e1 = r1 + 4; if (e1 > IMG) e1 = IMG;
            int a2 = r0 - 2; if (a2 < 0) a2 = 0;
            int e2 = r1 + 2; if (e2 > IMG) e2 = IMG;
            conv1_mfma<<<dim3(32, (e1 - a1 + 7) / 8), 256, 0, stream>>>(nh, nl, w1p, b1, h1h, h1l, a1, e1);
            conv2_mfma<<<dim3(32, (e2 - a2 + 7) / 8), 256, 0, stream>>>(h1h, h1l, w2p, b2, h2h, h2l, a1, e1, a2, e2);
            conv3_mfma<<<dim3(32, (r1 - r0 + 7) / 8), 256, 0, stream>>>(h2h, h2l, w3p, b3, lgb, a2, e2, r0, r1, rowsL);
            final_kernel<<<dim3(16, (r1 - r0 + 15) / 16), 256, 0, stream>>>(inb, lgb, dw, outb, r0, r1, rowsL);
        }
    }
}